// Round 1
// baseline (2746.202 us; speedup 1.0000x reference)
//
#include <hip/hip_runtime.h>
#include <hip/hip_fp16.h>

#define TLEN 16000

typedef _Float16 h16;
typedef __attribute__((ext_vector_type(8))) _Float16 half8;
typedef __attribute__((ext_vector_type(4))) _Float16 half4;
typedef __attribute__((ext_vector_type(4))) float f32x4;

// tanh(g)*sigmoid(g), stable for g << 0
__device__ __forceinline__ float gated_act(float g) {
  float gc = fmaxf(g, -30.0f);
  float e1 = __expf(-gc);
  float e2 = e1 * e1;
  return (1.0f - e2) / ((1.0f + e2) * (1.0f + e1));
}

// ---------------- prep: f32 -> f16 weight repack (runs every call; ws is re-poisoned) ----
// w2h  [l][o<256][k=512]: k<256 -> dilate_w[l][o][k][0] (shifted tap), else tap1
// resh [l][o][i], skiph [s][l*256+c], couth [o][s], cendh [p][o], sbias[s]=sum_l skip_b[l][s]
__global__ __launch_bounds__(256) void prep_k(
    const float* __restrict__ dw, const float* __restrict__ rw,
    const float* __restrict__ sw, const float* __restrict__ cow,
    const float* __restrict__ cew, const float* __restrict__ sb,
    h16* __restrict__ w2h, h16* __restrict__ resh, h16* __restrict__ skiph,
    h16* __restrict__ couth, h16* __restrict__ cendh, float* __restrict__ sbias)
{
  size_t u = (size_t)blockIdx.x * 256 + threadIdx.x;
  if (u < 2097152) {  // 16*256*512
    int l = (int)(u >> 17);
    int rem = (int)(u & 131071);
    int o = rem >> 9, k = rem & 511;
    float v = (k < 256) ? dw[(((size_t)l * 512 + o) * 256 + k) * 2]
                        : dw[(((size_t)l * 512 + o) * 256 + (k - 256)) * 2 + 1];
    w2h[u] = (h16)v;
    return;
  }
  u -= 2097152;
  if (u < 983040) { resh[u] = (h16)rw[u]; return; }  // 15*256*256 direct
  u -= 983040;
  if (u < 2097152) {  // 512*4096
    int s = (int)(u >> 12);
    int r = (int)(u & 4095);
    int l = r >> 8, c = r & 255;
    skiph[u] = (h16)sw[((size_t)l * 512 + s) * 256 + c];
    return;
  }
  u -= 2097152;
  if (u < 131072) { couth[u] = (h16)cow[u]; return; }
  u -= 131072;
  if (u < 65536) { cendh[u] = (h16)cew[u]; return; }
  u -= 65536;
  if (u < 512) {
    float s = 0.f;
    for (int l = 0; l < 16; l++) s += sb[(size_t)l * 512 + u];
    sbias[u] = s;
  }
}

// ---------------- embedding: x[b][t][c] = embed[tok[b][t]][c] (f32) ----------------
__global__ __launch_bounds__(256) void embed_k(
    const int* __restrict__ tok, const float* __restrict__ emb, float* __restrict__ x)
{
  const size_t i = (size_t)blockIdx.x * 256 + threadIdx.x;  // 4 floats / thread
  const size_t bt = i >> 6;
  const int c4 = (int)(i & 63) * 4;
  const int tk = tok[bt];
  *(f32x4*)(x + bt * 256 + c4) = *(const f32x4*)(emb + (size_t)tk * 256 + c4);
}

// ---------------- generic MFMA GEMM: D[t][n] = sum_k A[t][k] * W[n][k] ----------------
// Tile: M(t)=64, N=128, Kstep=32; 4 waves as 2x2, wave tile 32x64 (2x4 16x16x32 f16 MFMAs).
// MODE 0: dilate  (A = x f32, K=512 concat shift; epi: +bias, tanh*sigmoid -> act fp16)
// MODE 1: res     (A = act_l fp16, K=256; epi: x += D + bias, in-place f32)
// MODE 2: skip    (A = act[l][b][t][c] fp16, K=4096; epi: +sbias, relu -> sk16 fp16 [.][512])
// MODE 3: h1      (A = sk16 fp16 stride 512, K=512; epi: relu -> h1 fp16)
template<int KTOT, int MODE>
__global__ __launch_bounds__(256) void gemm_k(
    const void* __restrict__ Ag, const h16* __restrict__ W,
    const float* __restrict__ bias, void* __restrict__ Og,
    float* __restrict__ xres, int Bc)
{
  __shared__ h16 As[64][40];   // +8 halves pad: 80B row stride, 16B aligned, 2-way banks
  __shared__ h16 Bs[128][40];

  const int tid  = threadIdx.x;
  const int b    = blockIdx.z;
  const int t0   = blockIdx.x * 64;
  const int n0   = blockIdx.y * 128;
  const int lane = tid & 63;
  const int wid  = tid >> 6;
  const int wm   = wid >> 1;
  const int wn   = wid & 1;
  const int r16  = lane & 15;
  const int kg   = lane >> 4;

  f32x4 acc[2][4];
#pragma unroll
  for (int i = 0; i < 2; i++)
#pragma unroll
    for (int j = 0; j < 4; j++) acc[i][j] = (f32x4){0.f, 0.f, 0.f, 0.f};

  const int arow = tid >> 2, asub = tid & 3;   // A: 64 rows, 4 thr/row * 8 elems
  const int brow = tid >> 1, bsub = tid & 1;   // B: 128 rows, 2 thr/row * 16 halves
  const int t_a  = t0 + arow;

  for (int k0 = 0; k0 < KTOT; k0 += 32) {
    // ---- stage A tile [64][32]
    half8 av;
    if constexpr (MODE == 0) {
      const bool sh = (k0 < 256);
      const int c  = (k0 & 255) + asub * 8;
      const int st = sh ? (t_a - 256) : t_a;
      if (st >= 0) {
        const float* src = (const float*)Ag + ((size_t)b * TLEN + st) * 256 + c;
        f32x4 v0 = *(const f32x4*)(src);
        f32x4 v1 = *(const f32x4*)(src + 4);
#pragma unroll
        for (int j = 0; j < 4; j++) { av[j] = (h16)v0[j]; av[j + 4] = (h16)v1[j]; }
      } else {
#pragma unroll
        for (int j = 0; j < 8; j++) av[j] = (h16)0.f;
      }
    } else if constexpr (MODE == 2) {
      const int l = k0 >> 8, kk = k0 & 255;
      const h16* src = (const h16*)Ag + (((size_t)(l * Bc + b)) * TLEN + t_a) * 256 + kk + asub * 8;
      av = *(const half8*)src;
    } else {
      const int stride = (MODE == 3) ? 512 : 256;
      const h16* src = (const h16*)Ag + ((size_t)b * TLEN + t_a) * stride + k0 + asub * 8;
      av = *(const half8*)src;
    }
    *(half8*)&As[arow][asub * 8] = av;

    // ---- stage B tile [128][32] from W rows [n][KTOT]
    {
      const h16* src = W + (size_t)(n0 + brow) * KTOT + k0 + bsub * 16;
      *(half8*)&Bs[brow][bsub * 16]     = *(const half8*)(src);
      *(half8*)&Bs[brow][bsub * 16 + 8] = *(const half8*)(src + 8);
    }
    __syncthreads();

    half8 af[2], bf[4];
#pragma unroll
    for (int mi = 0; mi < 2; mi++) af[mi] = *(const half8*)&As[wm * 32 + mi * 16 + r16][kg * 8];
#pragma unroll
    for (int ni = 0; ni < 4; ni++) bf[ni] = *(const half8*)&Bs[wn * 64 + ni * 16 + r16][kg * 8];
#pragma unroll
    for (int mi = 0; mi < 2; mi++)
#pragma unroll
      for (int ni = 0; ni < 4; ni++)
        acc[mi][ni] = __builtin_amdgcn_mfma_f32_16x16x32_f16(af[mi], bf[ni], acc[mi][ni], 0, 0, 0);
    __syncthreads();
  }

  // ---- epilogue: D row = (lane>>4)*4 + reg, col = lane&15 (guide-verified C/D layout)
#pragma unroll
  for (int mi = 0; mi < 2; mi++) {
    const int tl = t0 + wm * 32 + mi * 16 + kg * 4;
#pragma unroll
    for (int ni = 0; ni < 4; ni++) {
      const int n = n0 + wn * 64 + ni * 16 + r16;
#pragma unroll
      for (int g = 0; g < 4; g++) {
        float v = acc[mi][ni][g];
        const int t = tl + g;
        if constexpr (MODE == 0) {
          v += bias[n];
          ((h16*)Og)[((size_t)b * TLEN + t) * 256 + n] = (h16)gated_act(v);
        } else if constexpr (MODE == 1) {
          const size_t idx = ((size_t)b * TLEN + t) * 256 + n;
          xres[idx] = xres[idx] + v + bias[n];
        } else if constexpr (MODE == 2) {
          v = fmaxf(v + bias[n], 0.f);
          ((h16*)Og)[((size_t)b * TLEN + t) * 512 + n] = (h16)v;
        } else {
          ((h16*)Og)[((size_t)b * TLEN + t) * 256 + n] = (h16)fmaxf(v, 0.f);
        }
      }
    }
  }
}

// ---------------- head: logits = h1 @ cend^T (K=256, N=256 full) + softmax + (B,O,T) write
__global__ __launch_bounds__(256) void head_k(
    const h16* __restrict__ A, const h16* __restrict__ W, float* __restrict__ out)
{
  __shared__ h16 As[32][40];
  __shared__ h16 Bs[256][40];
  __shared__ float lg[32][257];  // +1 pad: conflict-free column reads

  const int tid = threadIdx.x;
  const int b   = blockIdx.z;
  const int t0  = blockIdx.x * 32;
  const int lane = tid & 63, wid = tid >> 6;
  const int r16 = lane & 15, kg = lane >> 4;

  f32x4 acc[2][4];
#pragma unroll
  for (int i = 0; i < 2; i++)
#pragma unroll
    for (int j = 0; j < 4; j++) acc[i][j] = (f32x4){0.f, 0.f, 0.f, 0.f};

  const int arow = tid >> 3, asub = tid & 7;

  for (int k0 = 0; k0 < 256; k0 += 32) {
    {
      const h16* src = A + ((size_t)b * TLEN + t0 + arow) * 256 + k0 + asub * 4;
      *(half4*)&As[arow][asub * 4] = *(const half4*)src;
    }
    {
      const h16* src = W + (size_t)tid * 256 + k0;
#pragma unroll
      for (int q = 0; q < 4; q++) *(half8*)&Bs[tid][q * 8] = *(const half8*)(src + q * 8);
    }
    __syncthreads();
    half8 af[2], bf[4];
#pragma unroll
    for (int mi = 0; mi < 2; mi++) af[mi] = *(const half8*)&As[mi * 16 + r16][kg * 8];
#pragma unroll
    for (int ni = 0; ni < 4; ni++) bf[ni] = *(const half8*)&Bs[wid * 64 + ni * 16 + r16][kg * 8];
#pragma unroll
    for (int mi = 0; mi < 2; mi++)
#pragma unroll
      for (int ni = 0; ni < 4; ni++)
        acc[mi][ni] = __builtin_amdgcn_mfma_f32_16x16x32_f16(af[mi], bf[ni], acc[mi][ni], 0, 0, 0);
    __syncthreads();
  }

  // logits -> LDS
#pragma unroll
  for (int mi = 0; mi < 2; mi++) {
    const int rl = mi * 16 + kg * 4;
#pragma unroll
    for (int ni = 0; ni < 4; ni++) {
      const int n = wid * 64 + ni * 16 + r16;
#pragma unroll
      for (int g = 0; g < 4; g++) lg[rl + g][n] = acc[mi][ni][g];
    }
  }
  __syncthreads();

  // softmax over 256 channels; wave handles 8 rows, 4 vals/lane, shfl_xor reduce (wave=64)
  for (int i = 0; i < 8; i++) {
    const int r = wid * 8 + i;
    float v[4];
#pragma unroll
    for (int j = 0; j < 4; j++) v[j] = lg[r][lane + 64 * j];
    float m = fmaxf(fmaxf(v[0], v[1]), fmaxf(v[2], v[3]));
#pragma unroll
    for (int off = 32; off >= 1; off >>= 1) m = fmaxf(m, __shfl_xor(m, off));
    float s = 0.f;
#pragma unroll
    for (int j = 0; j < 4; j++) { v[j] = __expf(v[j] - m); s += v[j]; }
#pragma unroll
    for (int off = 32; off >= 1; off >>= 1) s += __shfl_xor(s, off);
    const float inv = 1.f / s;
#pragma unroll
    for (int j = 0; j < 4; j++) lg[r][lane + 64 * j] = v[j] * inv;
  }
  __syncthreads();

  // transposed coalesced write: out[b][o][t], 32 consecutive t per 32-lane group
  const int tl = tid & 31, og = tid >> 5;
  for (int j = 0; j < 32; j++) {
    const int o = og * 32 + j;
    out[((size_t)b * 256 + o) * TLEN + t0 + tl] = lg[tl][o];
  }
}

extern "C" void kernel_launch(void* const* d_in, const int* in_sizes, int n_in,
                              void* d_out, int out_size, void* d_ws, size_t ws_size,
                              hipStream_t stream)
{
  const int*   tokens = (const int*)  d_in[0];
  const float* embedw = (const float*)d_in[1];
  const float* dil_w  = (const float*)d_in[2];
  const float* dil_b  = (const float*)d_in[3];
  const float* resw   = (const float*)d_in[4];
  const float* resb   = (const float*)d_in[5];
  const float* skipw  = (const float*)d_in[6];
  const float* skipb  = (const float*)d_in[7];
  const float* coutw  = (const float*)d_in[8];
  const float* cendw  = (const float*)d_in[9];
  float* out = (float*)d_out;

  char* p = (char*)d_ws;
  auto carve = [&](size_t bytes) { char* r = p; p += (bytes + 255) & ~(size_t)255; return r; };
  h16* w2h     = (h16*)carve((size_t)16 * 256 * 512 * 2);
  h16* reshh   = (h16*)carve((size_t)15 * 256 * 256 * 2);
  h16* skiph   = (h16*)carve((size_t)512 * 4096 * 2);
  h16* couth   = (h16*)carve((size_t)256 * 512 * 2);
  h16* cendh   = (h16*)carve((size_t)256 * 256 * 2);
  float* sbias = (float*)carve(512 * 4);
  const size_t fixed = (size_t)(p - (char*)d_ws);

  // per-batch scratch: x f32 (sk16 aliases it) + act fp16 x16 layers (h1 aliases it)
  const size_t perB = (size_t)TLEN * 256 * 4 + (size_t)16 * TLEN * 256 * 2 + 1024;
  int Bc = 4;
  while (Bc > 1 && fixed + (size_t)Bc * perB > ws_size) Bc >>= 1;

  float* xbuf = (float*)carve((size_t)Bc * TLEN * 256 * 4);
  h16*   act  = (h16*) carve((size_t)16 * Bc * TLEN * 256 * 2);
  h16* sk16 = (h16*)xbuf;  // x dead after last dilate
  h16* h116 = (h16*)act;   // act dead after skip GEMM

  prep_k<<<dim3((5374464 + 255) / 256), 256, 0, stream>>>(
      dil_w, resw, skipw, coutw, cendw, skipb, w2h, reshh, skiph, couth, cendh, sbias);

  for (int c0 = 0; c0 < 4; c0 += Bc) {
    const int* tk = tokens + (size_t)c0 * TLEN;
    float* op = out + (size_t)c0 * 256 * TLEN;

    embed_k<<<dim3(Bc * 4000), 256, 0, stream>>>(tk, embedw, xbuf);

    for (int l = 0; l < 16; l++) {
      gemm_k<512, 0><<<dim3(250, 2, Bc), 256, 0, stream>>>(
          xbuf, w2h + (size_t)l * 256 * 512, dil_b + (size_t)l * 512,
          act + (size_t)l * Bc * TLEN * 256, nullptr, Bc);
      if (l < 15)
        gemm_k<256, 1><<<dim3(250, 2, Bc), 256, 0, stream>>>(
            act + (size_t)l * Bc * TLEN * 256, reshh + (size_t)l * 256 * 256,
            resb + (size_t)l * 256, nullptr, xbuf, Bc);
    }

    gemm_k<4096, 2><<<dim3(250, 4, Bc), 256, 0, stream>>>(act, skiph, sbias, sk16, nullptr, Bc);
    gemm_k<512, 3><<<dim3(250, 2, Bc), 256, 0, stream>>>(sk16, couth, nullptr, h116, nullptr, Bc);
    head_k<<<dim3(500, 1, Bc), 256, 0, stream>>>(h116, cendh, op);
  }
}

// Round 3
// 2472.292 us; speedup vs baseline: 1.1108x; 1.1108x over previous
//
#include <hip/hip_runtime.h>
#include <hip/hip_fp16.h>

#define TLEN 16000
#define BC 2          // batches per launch wave (2 chunks of 2)
#define XPROWS 16256  // TLEN + 256 pad rows for dilated tap

typedef _Float16 h16;
typedef __attribute__((ext_vector_type(8))) _Float16 half8;
typedef __attribute__((ext_vector_type(4))) _Float16 half4;
typedef __attribute__((ext_vector_type(4))) float f32x4;

// async global->LDS, 16B/lane; LDS base wave-uniform (lane*16 auto-offset)
__device__ __forceinline__ void gload16(const void* g, void* l) {
  __builtin_amdgcn_global_load_lds((const __attribute__((address_space(1))) void*)g,
                                   (__attribute__((address_space(3))) void*)l, 16, 0, 0);
}

// tanh(g)*sigmoid(g), stable for g << 0
__device__ __forceinline__ float gated_act(float g) {
  float gc = fmaxf(g, -30.0f);
  float e1 = __expf(-gc);
  float e2 = e1 * e1;
  return (1.0f - e2) / ((1.0f + e2) * (1.0f + e1));
}

// ---------------- prep: weight repack f32->f16, skip-bias fold, x16p pad zero ---------
// w2h  [l][o<256][k=512]  (k<256: tap0/shifted, else tap1)
// rs_w [l][768][256]: rows 0..255 res_w[l] (l<15), rows 256..767 skip_w[l]
// couth[o][s], cendh[p][o], sbias[s]=sum_l skip_b[l][s]
__global__ __launch_bounds__(256) void prep_k(
    const float* __restrict__ dw, const float* __restrict__ rw,
    const float* __restrict__ sw, const float* __restrict__ cow,
    const float* __restrict__ cew, const float* __restrict__ sb,
    h16* __restrict__ w2h, h16* __restrict__ rsw, h16* __restrict__ couth,
    h16* __restrict__ cendh, float* __restrict__ sbias, h16* __restrict__ x16p)
{
  size_t u = (size_t)blockIdx.x * 256 + threadIdx.x;
  if (u < 2097152) {
    int l = (int)(u >> 17);
    int rem = (int)(u & 131071);
    int o = rem >> 9, k = rem & 511;
    float v = (k < 256) ? dw[(((size_t)l * 512 + o) * 256 + k) * 2]
                        : dw[(((size_t)l * 512 + o) * 256 + (k - 256)) * 2 + 1];
    w2h[u] = (h16)v;
    return;
  }
  u -= 2097152;
  if (u < 3145728) {  // rs_w
    int l = (int)(u / 196608);
    int r = (int)(u % 196608);
    int row = r >> 8, c = r & 255;
    float v;
    if (row < 256) v = (l < 15) ? rw[((size_t)l * 256 + row) * 256 + c] : 0.f;
    else           v = sw[((size_t)l * 512 + (row - 256)) * 256 + c];
    rsw[u] = (h16)v;
    return;
  }
  u -= 3145728;
  if (u < 131072) { couth[u] = (h16)cow[u]; return; }
  u -= 131072;
  if (u < 65536) { cendh[u] = (h16)cew[u]; return; }
  u -= 65536;
  if (u < 512) {
    float s = 0.f;
    for (int l = 0; l < 16; l++) s += sb[(size_t)l * 512 + u];
    sbias[u] = s;
    return;
  }
  u -= 512;
  if (u < 131072) {  // zero pad rows [0,256) of both batches' x16p
    int b = (int)(u >> 16), off = (int)(u & 65535);
    x16p[(size_t)b * XPROWS * 256 + off] = (h16)0.f;
  }
}

// ---------------- embedding: xf32[b][t][c] and x16p[b][t+256][c] ----------------
__global__ __launch_bounds__(256) void embed_k(
    const int* __restrict__ tok, const float* __restrict__ emb,
    float* __restrict__ x, h16* __restrict__ x16p)
{
  const int b = blockIdx.y;
  const size_t i = (size_t)blockIdx.x * 256 + threadIdx.x;  // 4 floats / thread
  const int t = (int)(i >> 6);
  const int c4 = (int)(i & 63) * 4;
  const int tk = tok[(size_t)b * TLEN + t];
  f32x4 v = *(const f32x4*)(emb + (size_t)tk * 256 + c4);
  *(f32x4*)(x + ((size_t)b * TLEN + t) * 256 + c4) = v;
  half4 hv;
#pragma unroll
  for (int j = 0; j < 4; j++) hv[j] = (h16)v[j];
  *(half4*)(x16p + (size_t)b * XPROWS * 256 + (size_t)(t + 256) * 256 + c4) = hv;
}

// ---------------- skip init: skipf32[b][t][s] = sbias[s] ----------------
__global__ __launch_bounds__(256) void skipinit_k(
    const float* __restrict__ sbias, float* __restrict__ skip)
{
  const int b = blockIdx.y;
  const size_t i = (size_t)blockIdx.x * 256 + threadIdx.x;  // 4 f32 / thread
  const int t = (int)(i >> 7);
  const int s4 = (int)(i & 127) * 4;
  *(f32x4*)(skip + ((size_t)b * TLEN + t) * 512 + s4) = *(const f32x4*)(sbias + s4);
}

// ---------------- relu+convert: sk16 = (h16)relu(skipf32) ----------------
__global__ __launch_bounds__(256) void cvt_k(
    const float* __restrict__ skip, h16* __restrict__ sk16)
{
  const size_t i = ((size_t)blockIdx.y * 8192000) + ((size_t)blockIdx.x * 256 + threadIdx.x) * 4;
  f32x4 v = *(const f32x4*)(skip + i);
  half4 hv;
#pragma unroll
  for (int j = 0; j < 4; j++) hv[j] = (h16)fmaxf(v[j], 0.f);
  *(half4*)(sk16 + i) = hv;
}

// ---------------- 2-phase dbuf MFMA GEMM: D[t][n] = sum_k A[t][k]*W[n][k] ------------
// BM=64, BN=256, BK=32; 256 thr = 4 waves (1m x 4n), wave tile 64x64, acc[4][4].
// Linear LDS [rows][32] staged via global_load_lds w16; double-buffered, ONE barrier/step.
// MODE 0: dilate  A=x16p (pad rows; k<256 = shifted tap) -> act = gated(D + dil_b)
// MODE 1: res+skip fused. W=[res(256);skip(512)] rows, grid.y picks 256-row section.
//         res block: xf32 += D+resb (RMW), x16p = (h16)xf32.  skip block: skipf32 += D.
// MODE 2: h1      A=sk16 stride 512 -> h116 = relu(D)
template<int KTOT, int MODE>
__global__ __launch_bounds__(256) void gemm3_k(
    const h16* __restrict__ A, const h16* __restrict__ W,
    const float* __restrict__ bias, h16* __restrict__ o16,
    float* __restrict__ of32, float* __restrict__ ofskip, int nskip0)
{
  constexpr int NT = KTOT / 32;
  __shared__ h16 As[2][64 * 32];
  __shared__ h16 Bs[2][256 * 32];
  __shared__ h16 tbuf[4][16][72];

  const int tid  = threadIdx.x;
  const int lane = tid & 63;
  const int w    = tid >> 6;
  const int r16  = lane & 15;
  const int kg   = lane >> 4;
  const int t0   = blockIdx.x * 64;
  const int by   = blockIdx.y;
  const int bz   = blockIdx.z;
  const int srow  = lane >> 2;
  const int sunit = (lane & 3) * 8;

  const h16* Ab;
  if constexpr (MODE == 0)      Ab = A + (size_t)bz * XPROWS * 256;
  else if constexpr (MODE == 1) Ab = A + (size_t)bz * TLEN * 256;
  else                          Ab = A + (size_t)bz * TLEN * 512;
  const int n0w = (MODE == 1) ? by * 256 : 0;

  auto stage = [&](int bi, int kk) {
    const int k0 = kk * 32;
    {
      const h16* src;
      if constexpr (MODE == 0)
        src = Ab + (size_t)(t0 + w * 16 + srow + (k0 < 256 ? 0 : 256)) * 256 + (k0 & 255) + sunit;
      else if constexpr (MODE == 1)
        src = Ab + (size_t)(t0 + w * 16 + srow) * 256 + k0 + sunit;
      else
        src = Ab + (size_t)(t0 + w * 16 + srow) * 512 + k0 + sunit;
      gload16(src, &As[bi][(w * 16) * 32]);
    }
#pragma unroll
    for (int q = 0; q < 4; q++) {
      const h16* src = W + (size_t)(n0w + w * 64 + q * 16 + srow) * KTOT + k0 + sunit;
      gload16(src, &Bs[bi][(w * 64 + q * 16) * 32]);
    }
  };

  f32x4 acc[4][4];
#pragma unroll
  for (int i = 0; i < 4; i++)
#pragma unroll
    for (int j = 0; j < 4; j++) acc[i][j] = (f32x4){0.f, 0.f, 0.f, 0.f};

  stage(0, 0);
  __syncthreads();  // compiler drains vmcnt before s_barrier

  for (int t = 0; t < NT; t++) {
    const int cur = t & 1;
    if (t + 1 < NT) stage(cur ^ 1, t + 1);  // prefetch overlaps ds_read+MFMA below
    half8 af[4], bf[4];
#pragma unroll
    for (int mi = 0; mi < 4; mi++)
      af[mi] = *(const half8*)&As[cur][(mi * 16 + r16) * 32 + kg * 8];
#pragma unroll
    for (int ni = 0; ni < 4; ni++)
      bf[ni] = *(const half8*)&Bs[cur][(w * 64 + ni * 16 + r16) * 32 + kg * 8];
#pragma unroll
    for (int mi = 0; mi < 4; mi++)
#pragma unroll
      for (int ni = 0; ni < 4; ni++)
        acc[mi][ni] = __builtin_amdgcn_mfma_f32_16x16x32_f16(af[mi], bf[ni], acc[mi][ni], 0, 0, 0);
    __syncthreads();  // one barrier/step: drains prefetch vmcnt + lgkm
  }

  // ---- epilogue
  const int rr = lane >> 2;
  const int cc = (lane & 3) * 16;
  const bool is_res = (MODE == 1) && (n0w < nskip0);

  if constexpr (MODE == 1) {
    if (!is_res) {  // skip block: direct f32 accumulate, no transpose needed
#pragma unroll
      for (int mi = 0; mi < 4; mi++)
#pragma unroll
        for (int ni = 0; ni < 4; ni++) {
          const int s = n0w + w * 64 + ni * 16 + r16 - nskip0;
#pragma unroll
          for (int g = 0; g < 4; g++) {
            const int t = t0 + mi * 16 + kg * 4 + g;
            const size_t ix = ((size_t)bz * TLEN + t) * 512 + s;
            ofskip[ix] += acc[mi][ni][g];
          }
        }
      return;
    }
  }

#pragma unroll
  for (int mi = 0; mi < 4; mi++) {
#pragma unroll
    for (int ni = 0; ni < 4; ni++) {
      const int nl = w * 64 + ni * 16 + r16;
#pragma unroll
      for (int g = 0; g < 4; g++) {
        float v = acc[mi][ni][g];
        const int t = t0 + mi * 16 + kg * 4 + g;
        if constexpr (MODE == 0) {
          v = gated_act(v + bias[nl]);
        } else if constexpr (MODE == 1) {  // res block
          const size_t ix = ((size_t)bz * TLEN + t) * 256 + nl;
          v = of32[ix] + v + bias[nl];
          of32[ix] = v;  // f32 residual master
        } else {
          v = fmaxf(v, 0.f);
        }
        tbuf[w][kg * 4 + g][ni * 16 + r16] = (h16)v;
      }
    }
    // coalesced 32B h16 row stores (same-wave LDS RAW is in-order)
    h16* dst;
    if constexpr (MODE == 1)
      dst = o16 + (size_t)bz * XPROWS * 256 + (size_t)(256 + t0 + mi * 16 + rr) * 256 + w * 64 + cc;
    else
      dst = o16 + ((size_t)bz * TLEN + t0 + mi * 16 + rr) * 256 + w * 64 + cc;
    *(half8*)dst       = *(const half8*)&tbuf[w][rr][cc];
    *(half8*)(dst + 8) = *(const half8*)&tbuf[w][rr][cc + 8];
  }
}

// ---------------- head: logits = h1 @ cend^T (K=256,N=256) + softmax + (O,T) write ----
__global__ __launch_bounds__(256) void head_k(
    const h16* __restrict__ A, const h16* __restrict__ W, float* __restrict__ out)
{
  __shared__ h16 As[32][40];
  __shared__ h16 Bs[256][40];
  __shared__ float lg[32][257];

  const int tid = threadIdx.x;
  const int bz  = blockIdx.z;
  const int t0  = blockIdx.x * 32;
  const int lane = tid & 63, wid = tid >> 6;
  const int r16 = lane & 15, kg = lane >> 4;
  const h16* Ab = A + (size_t)bz * TLEN * 256;

  f32x4 acc[2][4];
#pragma unroll
  for (int i = 0; i < 2; i++)
#pragma unroll
    for (int j = 0; j < 4; j++) acc[i][j] = (f32x4){0.f, 0.f, 0.f, 0.f};

  const int arow = tid >> 3, asub = tid & 7;

  for (int k0 = 0; k0 < 256; k0 += 32) {
    {
      const h16* src = Ab + (size_t)(t0 + arow) * 256 + k0 + asub * 4;
      *(half4*)&As[arow][asub * 4] = *(const half4*)src;
    }
    {
      const h16* src = W + (size_t)tid * 256 + k0;
#pragma unroll
      for (int q = 0; q < 4; q++) *(half8*)&Bs[tid][q * 8] = *(const half8*)(src + q * 8);
    }
    __syncthreads();
    half8 af[2], bf[4];
#pragma unroll
    for (int mi = 0; mi < 2; mi++) af[mi] = *(const half8*)&As[mi * 16 + r16][kg * 8];
#pragma unroll
    for (int ni = 0; ni < 4; ni++) bf[ni] = *(const half8*)&Bs[wid * 64 + ni * 16 + r16][kg * 8];
#pragma unroll
    for (int mi = 0; mi < 2; mi++)
#pragma unroll
      for (int ni = 0; ni < 4; ni++)
        acc[mi][ni] = __builtin_amdgcn_mfma_f32_16x16x32_f16(af[mi], bf[ni], acc[mi][ni], 0, 0, 0);
    __syncthreads();
  }

#pragma unroll
  for (int mi = 0; mi < 2; mi++) {
    const int rl = mi * 16 + kg * 4;
#pragma unroll
    for (int ni = 0; ni < 4; ni++) {
      const int n = wid * 64 + ni * 16 + r16;
#pragma unroll
      for (int g = 0; g < 4; g++) lg[rl + g][n] = acc[mi][ni][g];
    }
  }
  __syncthreads();

  for (int i = 0; i < 8; i++) {
    const int r = wid * 8 + i;
    float v[4];
#pragma unroll
    for (int j = 0; j < 4; j++) v[j] = lg[r][lane + 64 * j];
    float m = fmaxf(fmaxf(v[0], v[1]), fmaxf(v[2], v[3]));
#pragma unroll
    for (int off = 32; off >= 1; off >>= 1) m = fmaxf(m, __shfl_xor(m, off));
    float s = 0.f;
#pragma unroll
    for (int j = 0; j < 4; j++) { v[j] = __expf(v[j] - m); s += v[j]; }
#pragma unroll
    for (int off = 32; off >= 1; off >>= 1) s += __shfl_xor(s, off);
    const float inv = 1.f / s;
#pragma unroll
    for (int j = 0; j < 4; j++) lg[r][lane + 64 * j] = v[j] * inv;
  }
  __syncthreads();

  const int tl = tid & 31, og = tid >> 5;
  for (int j = 0; j < 32; j++) {
    const int o = og * 32 + j;
    out[((size_t)bz * 256 + o) * TLEN + t0 + tl] = lg[tl][o];
  }
}

extern "C" void kernel_launch(void* const* d_in, const int* in_sizes, int n_in,
                              void* d_out, int out_size, void* d_ws, size_t ws_size,
                              hipStream_t stream)
{
  const int*   tokens = (const int*)  d_in[0];
  const float* embedw = (const float*)d_in[1];
  const float* dil_w  = (const float*)d_in[2];
  const float* dil_b  = (const float*)d_in[3];
  const float* resw   = (const float*)d_in[4];
  const float* resb   = (const float*)d_in[5];
  const float* skipw  = (const float*)d_in[6];
  const float* skipb  = (const float*)d_in[7];
  const float* coutw  = (const float*)d_in[8];
  const float* cendw  = (const float*)d_in[9];
  float* out = (float*)d_out;

  // ws budget: 142.2 MB total (round-1 proved >=158.2 MB available; round-2's 166.5 MB
  // overflowed and corrupted neighboring allocations -> post-timing divergence)
  char* p = (char*)d_ws;
  auto carve = [&](size_t bytes) { char* r = p; p += (bytes + 255) & ~(size_t)255; return r; };
  h16* w2h      = (h16*)carve((size_t)16 * 256 * 512 * 2);        //  4.19 MB
  h16* rsw      = (h16*)carve((size_t)16 * 768 * 256 * 2);        //  6.29 MB
  h16* couth    = (h16*)carve((size_t)256 * 512 * 2);             //  0.26 MB
  h16* cendh    = (h16*)carve((size_t)256 * 256 * 2);             //  0.13 MB
  float* sbias  = (float*)carve(512 * 4);
  float* xf32   = (float*)carve((size_t)BC * TLEN * 256 * 4);     // 32.77 MB
  h16*  x16p    = (h16*) carve((size_t)BC * XPROWS * 256 * 2);    // 16.65 MB
  h16*  act     = (h16*) carve((size_t)BC * TLEN * 256 * 2);      // 16.38 MB
  float* skipf  = (float*)carve((size_t)BC * TLEN * 512 * 4);     // 65.54 MB
  h16* sk16 = (h16*)xf32;  // xf32 dead after l=14 res RMW
  h16* h116 = act;         // act dead after l=15 RS

  prep_k<<<dim3(21762), 256, 0, stream>>>(
      dil_w, resw, skipw, coutw, cendw, skipb, w2h, rsw, couth, cendh, sbias, x16p);

  for (int c0 = 0; c0 < 4; c0 += BC) {
    const int* tk = tokens + (size_t)c0 * TLEN;

    embed_k<<<dim3(4000, BC), 256, 0, stream>>>(tk, embedw, xf32, x16p);
    skipinit_k<<<dim3(8000, BC), 256, 0, stream>>>(sbias, skipf);

    for (int l = 0; l < 16; l++) {
      gemm3_k<512, 0><<<dim3(250, 1, BC), 256, 0, stream>>>(
          x16p, w2h + (size_t)l * 131072, dil_b + (size_t)l * 512,
          act, nullptr, nullptr, 0);
      if (l < 15)
        gemm3_k<256, 1><<<dim3(250, 3, BC), 256, 0, stream>>>(
            act, rsw + (size_t)l * 196608, resb + (size_t)l * 256,
            x16p, xf32, skipf, 256);
      else  // last layer: skip contribution only (rows 256..767 of rs_w[15])
        gemm3_k<256, 1><<<dim3(250, 2, BC), 256, 0, stream>>>(
            act, rsw + (size_t)15 * 196608 + 65536, nullptr,
            x16p, xf32, skipf, 0);
    }

    cvt_k<<<dim3(8000, BC), 256, 0, stream>>>(skipf, sk16);
    gemm3_k<512, 2><<<dim3(250, 1, BC), 256, 0, stream>>>(
        sk16, couth, nullptr, h116, nullptr, nullptr, 0);
    head_k<<<dim3(500, 1, BC), 256, 0, stream>>>(h116, cendh, out + (size_t)c0 * 256 * TLEN);
  }
}